// Round 10
// baseline (652.413 us; speedup 1.0000x reference)
//
#include <hip/hip_runtime.h>

#define BATCH 4
#define NPTS  131072
#define KSEL  128
#define FDIM  96
#define QDIM  128

#define G   32                   // workgroups per batch
#define T   512                  // threads per workgroup
#define P   (NPTS / (G * T))     // 8 points per thread (registers)
#define NW  (T / 64)             // 8 waves per WG
#define NBLK 256                 // total blocks (1 per CU)

#define AG __HIP_MEMORY_SCOPE_AGENT
#define WGS __HIP_MEMORY_SCOPE_WORKGROUP

#define FAST_CAP 32              // bounded budget for the unproven sc0 poll

// ---- workspace (261248 B <= proven 262144 budget) ----
// slots[BATCH][KSEL-1][G] u64, fparts[BATCH][KSEL][G] u64, ctrl block
#define SLOTS_SZ  (BATCH * (KSEL - 1) * G * 8)   // 130048
#define FPART_SZ  (BATCH * KSEL * G * 8)         // 131072
#define FPART_OFF (SLOTS_SZ)
#define CTRL_OFF  (SLOTS_SZ + FPART_SZ)          // xcd_rank[8] u32 + arrivals u32
#define WS_TOTAL  (CTRL_OFF + 128)

// d2 exactly as numpy: (dx*dx + dy*dy) + dz*dz, no FMA contraction
__device__ __forceinline__ float d2_np(float ax, float ay, float az,
                                       float bx, float by, float bz) {
    float dx = __fsub_rn(ax, bx);
    float dy = __fsub_rn(ay, by);
    float dz = __fsub_rn(az, bz);
    return __fadd_rn(__fadd_rn(__fmul_rn(dx, dx), __fmul_rn(dy, dy)),
                     __fmul_rn(dz, dz));
}

__device__ __forceinline__ unsigned long long pack_key(float v, unsigned n) {
    // (d2_bits << 32) | ~n : max == (max d2, then min index); never 0 for valid n
    return ((unsigned long long)__float_as_uint(v) << 32) | (unsigned)(~n);
}

// L1-bypass load (L2-served). Validity is NOT assumed: used only inside a
// bounded loop with a proven agent-scope fallback.
__device__ __forceinline__ unsigned long long ld_sc0_u64(const unsigned long long* p) {
    unsigned long long r;
    asm volatile("global_load_dwordx2 %0, %1, off sc0\n\t"
                 "s_waitcnt vmcnt(0)" : "=v"(r) : "v"(p) : "memory");
    return r;
}

__global__ __launch_bounds__(T) void fps_kernel(
    const float* __restrict__ coords,          // [BATCH][NPTS][3]
    unsigned long long* __restrict__ slots,    // [BATCH][KSEL-1][G]
    unsigned long long* __restrict__ fparts,   // [BATCH][KSEL][G]
    unsigned int* __restrict__ ctrl,           // xcd_rank[8], arrivals at [8]
    float* __restrict__ out_sc)                // [BATCH][KSEL][3]
{
    const int blk  = blockIdx.x;
    const int tid  = threadIdx.x;
    const int wid  = tid >> 6;
    const int lane = tid & 63;

    __shared__ unsigned s_rank, s_mode;
    __shared__ unsigned long long s_md[NW];
    __shared__ unsigned long long s_ft[NW];
    __shared__ float s_samp[KSEL][3];
    __shared__ float s_cur[3];

    // ---- one-time registration & mode decision (proven atomics) ----
    unsigned xcc;
    asm volatile("s_getreg_b32 %0, hwreg(HW_REG_XCC_ID)" : "=s"(xcc));
    xcc &= 7;
    if (tid == 0) {
        unsigned rk = __hip_atomic_fetch_add(&ctrl[xcc], 1u,
                                             __ATOMIC_RELAXED, AG);
        __hip_atomic_fetch_add(&ctrl[8], 1u, __ATOMIC_RELEASE, AG);
        while (__hip_atomic_load(&ctrl[8], __ATOMIC_ACQUIRE, AG) < (unsigned)NBLK) {
            __builtin_amdgcn_s_sleep(1);
        }
        unsigned ok = 1;
        #pragma unroll
        for (int i = 0; i < 8; ++i)
            ok &= (__hip_atomic_load(&ctrl[i], __ATOMIC_RELAXED, AG) == (unsigned)G);
        s_rank = rk;
        s_mode = ok;          // 1 => mode A (xcd-local), 0 => mode B (R3)
    }
    __syncthreads();
    const bool fastm = (s_mode != 0);

    int b, wgb;
    if (fastm) {
        if ((int)xcc >= BATCH) return;         // XCDs 4-7 idle
        b = (int)xcc; wgb = (int)s_rank;       // 32 blocks on XCD b == batch b
    } else {
        if (blk >= BATCH * G) return;
        b = blk / G; wgb = blk % G;
    }

    const float* cb = coords + (size_t)b * NPTS * 3;
    const int base = wgb * T + tid;            // stride G*T between my points

    float px[P], py[P], pz[P], md[P];
    #pragma unroll
    for (int j = 0; j < P; ++j) {
        int n = base + j * (G * T);
        px[j] = cb[n * 3 + 0];
        py[j] = cb[n * 3 + 1];
        pz[j] = cb[n * 3 + 2];
        md[j] = 1e10f;
    }

    float cx = cb[0], cy = cb[1], cz = cb[2];  // sample 0 = index 0
    if (tid == 0) {
        s_samp[0][0] = cx; s_samp[0][1] = cy; s_samp[0][2] = cz;
    }
    __syncthreads();

    for (int s = 1; s < KSEL; ++s) {
        // update md; per-lane argmax of md (FPS) and of raw d2 (feat for s-1)
        float bm = -1.0f; unsigned bn = 0;
        float bd = -1.0f; unsigned fn = 0;
        #pragma unroll
        for (int j = 0; j < P; ++j) {
            float d2 = d2_np(px[j], py[j], pz[j], cx, cy, cz);
            unsigned n = (unsigned)(base + j * (G * T));
            if (d2 > bd) { bd = d2; fn = n; }
            float m = fminf(md[j], d2);
            md[j] = m;
            if (m > bm) { bm = m; bn = n; }
        }
        unsigned long long kmd = pack_key(bm, bn);
        unsigned long long kft = pack_key(bd, fn);
        #pragma unroll
        for (int off = 32; off > 0; off >>= 1) {
            unsigned long long o1 = __shfl_xor(kmd, off, 64);
            unsigned long long o2 = __shfl_xor(kft, off, 64);
            if (o1 > kmd) kmd = o1;
            if (o2 > kft) kft = o2;
        }
        if (lane == 0) { s_md[wid] = kmd; s_ft[wid] = kft; }
        __syncthreads();                       // barrier 1: partials ready

        if (wid == 0) {
            // merge the 8 wave partials, publish, poll, resolve
            unsigned long long k1 = (lane < NW) ? s_md[lane] : 0;
            unsigned long long k2 = (lane < NW) ? s_ft[lane] : 0;
            #pragma unroll
            for (int off = 4; off > 0; off >>= 1) {
                unsigned long long o1 = __shfl_xor(k1, off, 64);
                unsigned long long o2 = __shfl_xor(k2, off, 64);
                if (o1 > k1) k1 = o1;
                if (o2 > k2) k2 = o2;
            }
            const size_t row = ((size_t)b * (KSEL - 1) + (s - 1)) * G;
            if (lane == 0) {
                unsigned long long* sp = &slots[row + wgb];
                if (fastm)   // fast local-L2 copy (plain store, write-through L1)
                    __hip_atomic_store(sp, k1, __ATOMIC_RELAXED, WGS);
                // insurance: proven agent-scope store (MALL-visible)
                __hip_atomic_store(sp, k1, __ATOMIC_RELAXED, AG);
                fparts[((size_t)b * KSEL + (s - 1)) * G + wgb] = k2;
            }
            // poll all 32 slots (one lane each)
            unsigned long long k = 0;
            if (lane < G) {
                const unsigned long long* p = &slots[row + lane];
                if (fastm) {
                    for (int it = 0; it < FAST_CAP; ++it) {
                        k = ld_sc0_u64(p);
                        if (__ballot(k == 0) == 0) break;
                    }
                }
                while (k == 0) {               // proven-terminating fallback
                    k = __hip_atomic_load(p, __ATOMIC_RELAXED, AG);
                }
            }
            #pragma unroll
            for (int off = 32; off > 0; off >>= 1) {
                unsigned long long o = __shfl_xor(k, off, 64);
                if (o > k) k = o;
            }
            if (lane == 0) {
                int idx = (int)(~(unsigned)(k & 0xFFFFFFFFull));
                float wx = cb[idx * 3 + 0];    // read-only, cacheable
                float wy = cb[idx * 3 + 1];
                float wz = cb[idx * 3 + 2];
                s_cur[0] = wx; s_cur[1] = wy; s_cur[2] = wz;
                s_samp[s][0] = wx; s_samp[s][1] = wy; s_samp[s][2] = wz;
            }
        }
        __syncthreads();                       // barrier 2: winner broadcast
        cx = s_cur[0]; cy = s_cur[1]; cz = s_cur[2];
    }

    // feat partial for sample 127 (cx.. = sample 127 now)
    {
        float bd = -1.0f; unsigned fn = 0;
        #pragma unroll
        for (int j = 0; j < P; ++j) {
            float d2 = d2_np(px[j], py[j], pz[j], cx, cy, cz);
            unsigned n = (unsigned)(base + j * (G * T));
            if (d2 > bd) { bd = d2; fn = n; }
        }
        unsigned long long kft = pack_key(bd, fn);
        #pragma unroll
        for (int off = 32; off > 0; off >>= 1) {
            unsigned long long o = __shfl_xor(kft, off, 64);
            if (o > kft) kft = o;
        }
        if (lane == 0) s_ft[wid] = kft;
        __syncthreads();
        if (tid == 0) {
            unsigned long long k = s_ft[0];
            #pragma unroll
            for (int w = 1; w < NW; ++w)
                if (s_ft[w] > k) k = s_ft[w];
            fparts[((size_t)b * KSEL + (KSEL - 1)) * G + wgb] = k;
        }
    }

    // wgb 0 dumps all sampled coords once (off critical path)
    if (wgb == 0 && tid < KSEL * 3) {
        const float* sf = &s_samp[0][0];
        out_sc[(size_t)b * KSEL * 3 + tid] = sf[tid];
    }
}

__global__ __launch_bounds__(QDIM) void mlp_kernel(
    const float* __restrict__ features,   // [BATCH][NPTS][FDIM]
    const float* __restrict__ W1,         // [FDIM][QDIM]
    const float* __restrict__ b1,         // [QDIM]
    const float* __restrict__ W2,         // [QDIM][QDIM]
    const float* __restrict__ b2,         // [QDIM]
    const unsigned long long* __restrict__ fparts,  // [BATCH][KSEL][G]
    float* __restrict__ out_q)            // [BATCH][KSEL][QDIM]
{
    const int bk = blockIdx.x;            // b*KSEL + k
    const int b  = bk / KSEL;
    const int q  = threadIdx.x;
    const int lane = q & 63;

    __shared__ float fr[FDIM];
    __shared__ float h[QDIM];
    __shared__ int s_idx;

    if (q < 64) {
        unsigned long long k = 0;
        if (lane < G) k = fparts[(size_t)bk * G + lane];
        #pragma unroll
        for (int off = 32; off > 0; off >>= 1) {
            unsigned long long o = __shfl_xor(k, off, 64);
            if (o > k) k = o;
        }
        if (lane == 0) s_idx = (int)(~(unsigned)(k & 0xFFFFFFFFull));
    }
    __syncthreads();

    const float* frow = features + ((size_t)b * NPTS + s_idx) * FDIM;
    if (q < FDIM) fr[q] = frow[q];
    __syncthreads();

    float acc = b1[q];
    #pragma unroll 8
    for (int f = 0; f < FDIM; ++f) acc += fr[f] * W1[f * QDIM + q];
    h[q] = fmaxf(acc, 0.0f);
    __syncthreads();

    float acc2 = b2[q];
    #pragma unroll 8
    for (int j = 0; j < QDIM; ++j) acc2 += h[j] * W2[j * QDIM + q];
    out_q[(size_t)bk * QDIM + q] = acc2;
}

extern "C" void kernel_launch(void* const* d_in, const int* in_sizes, int n_in,
                              void* d_out, int out_size, void* d_ws, size_t ws_size,
                              hipStream_t stream) {
    (void)in_sizes; (void)n_in; (void)out_size; (void)ws_size;
    const float* coords   = (const float*)d_in[0];
    const float* features = (const float*)d_in[1];
    const float* W1       = (const float*)d_in[2];
    const float* b1       = (const float*)d_in[3];
    const float* W2       = (const float*)d_in[4];
    const float* b2       = (const float*)d_in[5];

    float* out_q  = (float*)d_out;
    float* out_sc = out_q + (size_t)BATCH * KSEL * QDIM;

    char* ws = (char*)d_ws;
    unsigned long long* slots  = (unsigned long long*)ws;
    unsigned long long* fparts = (unsigned long long*)(ws + FPART_OFF);
    unsigned int*       ctrl   = (unsigned int*)(ws + CTRL_OFF);

    hipMemsetAsync(d_ws, 0, WS_TOTAL, stream);
    fps_kernel<<<NBLK, T, 0, stream>>>(coords, slots, fparts, ctrl, out_sc);
    mlp_kernel<<<BATCH * KSEL, QDIM, 0, stream>>>(features, W1, b1, W2, b2,
                                                  fparts, out_q);
}

// Round 11
// 430.570 us; speedup vs baseline: 1.5152x; 1.5152x over previous
//
#include <hip/hip_runtime.h>

#define BATCH 4
#define NPTS  131072
#define KSEL  128
#define FDIM  96
#define QDIM  128

#define G   16                   // workgroups per batch
#define T   512                  // threads per workgroup
#define P   (NPTS / (G * T))     // 16 points per thread (registers)
#define NW  (T / 64)             // 8 waves per WG
#define NSLOT (G * NW)           // 128 wave-publish slots per (batch, parity)

#define AG __HIP_MEMORY_SCOPE_AGENT

// ---- workspace (~72 KiB, well under proven 256 KiB budget) ----
// slots[BATCH][2][NSLOT] u64 : parity-double-buffered, step-tagged wave partials
//   word = (d2_bits<<32) | (m<<8) | (s&0xFF),  m = NPTS-1-n  (17 bits)
//   max key == (max d2, then min index); tag disambiguates row reuse (s vs s-2)
// fparts[BATCH][KSEL][G] u64 : per-WG feat argmax partials (d2<<32 | ~n)
#define SLOTS_SZ  (BATCH * 2 * NSLOT * 8)        // 8 KiB
#define FPART_SZ  (BATCH * KSEL * G * 8)         // 64 KiB
#define FPART_OFF (SLOTS_SZ)
#define WS_TOTAL  (SLOTS_SZ + FPART_SZ)

// d2 exactly as numpy: (dx*dx + dy*dy) + dz*dz, no FMA contraction
__device__ __forceinline__ float d2_np(float ax, float ay, float az,
                                       float bx, float by, float bz) {
    float dx = __fsub_rn(ax, bx);
    float dy = __fsub_rn(ay, by);
    float dz = __fsub_rn(az, bz);
    return __fadd_rn(__fadd_rn(__fmul_rn(dx, dx), __fmul_rn(dy, dy)),
                     __fmul_rn(dz, dz));
}

__global__ __launch_bounds__(T) void fps_kernel(
    const float* __restrict__ coords,          // [BATCH][NPTS][3]
    unsigned long long* __restrict__ slots,    // [BATCH][2][NSLOT]
    unsigned long long* __restrict__ fparts,   // [BATCH][KSEL][G]
    float* __restrict__ out_sc)                // [BATCH][KSEL][3]
{
    const int b    = blockIdx.x / G;
    const int wgb  = blockIdx.x % G;
    const int tid  = threadIdx.x;
    const int wid  = tid >> 6;
    const int lane = tid & 63;
    const float* cb = coords + (size_t)b * NPTS * 3;
    const int base = wgb * T + tid;            // stride G*T = 8192 between points

    __shared__ unsigned long long s_ft[2][NW]; // parity-buffered feat partials
    __shared__ float s_samp[KSEL][3];
    __shared__ float s_cur[3];

    float px[P], py[P], pz[P], md[P];
    #pragma unroll
    for (int j = 0; j < P; ++j) {
        int n = base + j * (G * T);
        px[j] = cb[n * 3 + 0];
        py[j] = cb[n * 3 + 1];
        pz[j] = cb[n * 3 + 2];
        md[j] = 1e10f;
    }

    float cx = cb[0], cy = cb[1], cz = cb[2];  // sample 0 = index 0
    if (tid == 0) {
        s_samp[0][0] = cx; s_samp[0][1] = cy; s_samp[0][2] = cz;
    }
    __syncthreads();

    for (int s = 1; s < KSEL; ++s) {
        const int pb = s & 1;
        // update md; per-lane argmax of md (FPS) and of raw d2 (feat for s-1)
        float bm = -1.0f; unsigned bn = 0;
        float bd = -1.0f; unsigned fn = 0;
        #pragma unroll
        for (int j = 0; j < P; ++j) {
            float d2 = d2_np(px[j], py[j], pz[j], cx, cy, cz);
            unsigned n = (unsigned)(base + j * (G * T));
            if (d2 > bd) { bd = d2; fn = n; }
            float m = fminf(md[j], d2);
            md[j] = m;
            if (m > bm) { bm = m; bn = n; }
        }
        // pack: d2<<32 | (NPTS-1-n)<<8 | tag   (max == max d2, then min n)
        unsigned long long kmd =
            ((unsigned long long)__float_as_uint(bm) << 32) |
            ((unsigned long long)(NPTS - 1 - bn) << 8) |
            (unsigned long long)(s & 0xFF);
        unsigned long long kft =
            ((unsigned long long)__float_as_uint(bd) << 32) | (unsigned)(~fn);
        #pragma unroll
        for (int off = 32; off > 0; off >>= 1) {
            unsigned long long o1 = __shfl_xor(kmd, off, 64);
            unsigned long long o2 = __shfl_xor(kft, off, 64);
            if (o1 > kmd) kmd = o1;
            if (o2 > kft) kft = o2;
        }
        // WAVE-DIRECT publish: no barrier, no merge on the critical path
        if (lane == 0) {
            __hip_atomic_store(
                &slots[((size_t)(b * 2 + pb)) * NSLOT + wgb * NW + wid],
                kmd, __ATOMIC_RELAXED, AG);
            s_ft[pb][wid] = kft;               // LDS, consumed next step
        }

        if (wid == 1 && s >= 2) {
            // merge PREVIOUS step's feat partials (behind own publish;
            // s_ft[pb^1] was completed before the end-of-step-(s-1) barrier)
            unsigned long long k2 = (lane < NW) ? s_ft[pb ^ 1][lane] : 0;
            #pragma unroll
            for (int off = 4; off > 0; off >>= 1) {
                unsigned long long o = __shfl_xor(k2, off, 64);
                if (o > k2) k2 = o;
            }
            if (lane == 0)
                fparts[((size_t)b * KSEL + (s - 2)) * G + wgb] = k2;
        }

        if (wid == 0) {
            // poll all 128 slots of this step (2 per lane), tag-checked
            const unsigned long long* row =
                &slots[((size_t)(b * 2 + pb)) * NSLOT];
            const unsigned tag = (unsigned)(s & 0xFF);
            unsigned long long k0, k1;
            do {
                k0 = __hip_atomic_load(row + lane,      __ATOMIC_RELAXED, AG);
                k1 = __hip_atomic_load(row + 64 + lane, __ATOMIC_RELAXED, AG);
            } while (__ballot((((unsigned)k0 & 0xFFu) != tag) |
                              (((unsigned)k1 & 0xFFu) != tag)));
            unsigned long long k = k0 > k1 ? k0 : k1;
            #pragma unroll
            for (int off = 32; off > 0; off >>= 1) {
                unsigned long long o = __shfl_xor(k, off, 64);
                if (o > k) k = o;
            }
            if (lane == 0) {
                unsigned m = ((unsigned)k) >> 8;       // bits 8..24
                int idx = (int)(NPTS - 1u - m);
                float wx = cb[idx * 3 + 0];            // read-only, cacheable
                float wy = cb[idx * 3 + 1];
                float wz = cb[idx * 3 + 2];
                s_cur[0] = wx; s_cur[1] = wy; s_cur[2] = wz;
                s_samp[s][0] = wx; s_samp[s][1] = wy; s_samp[s][2] = wz;
            }
        }
        __syncthreads();                       // the ONLY barrier per step
        cx = s_cur[0]; cy = s_cur[1]; cz = s_cur[2];
    }

    // ---- tail ----
    // s_ft[1] holds feat partials for sample 126 (written during s=127).
    // Compute feat partial for sample 127 into s_ft[0] (free since s=126's
    // content was merged during s=127 by wave1).
    {
        float bd = -1.0f; unsigned fn = 0;
        #pragma unroll
        for (int j = 0; j < P; ++j) {
            float d2 = d2_np(px[j], py[j], pz[j], cx, cy, cz);
            unsigned n = (unsigned)(base + j * (G * T));
            if (d2 > bd) { bd = d2; fn = n; }
        }
        unsigned long long kft =
            ((unsigned long long)__float_as_uint(bd) << 32) | (unsigned)(~fn);
        #pragma unroll
        for (int off = 32; off > 0; off >>= 1) {
            unsigned long long o = __shfl_xor(kft, off, 64);
            if (o > kft) kft = o;
        }
        if (lane == 0) s_ft[0][wid] = kft;
    }
    __syncthreads();
    if (wid == 1) {                            // feat for sample 126
        unsigned long long k2 = (lane < NW) ? s_ft[1][lane] : 0;
        #pragma unroll
        for (int off = 4; off > 0; off >>= 1) {
            unsigned long long o = __shfl_xor(k2, off, 64);
            if (o > k2) k2 = o;
        }
        if (lane == 0)
            fparts[((size_t)b * KSEL + 126) * G + wgb] = k2;
    }
    if (wid == 0) {                            // feat for sample 127
        unsigned long long k2 = (lane < NW) ? s_ft[0][lane] : 0;
        #pragma unroll
        for (int off = 4; off > 0; off >>= 1) {
            unsigned long long o = __shfl_xor(k2, off, 64);
            if (o > k2) k2 = o;
        }
        if (lane == 0)
            fparts[((size_t)b * KSEL + 127) * G + wgb] = k2;
    }

    // wgb 0 dumps all sampled coords once (s_samp final since loop-end barrier)
    if (wgb == 0 && tid < KSEL * 3) {
        const float* sf = &s_samp[0][0];
        out_sc[(size_t)b * KSEL * 3 + tid] = sf[tid];
    }
}

__global__ __launch_bounds__(QDIM) void mlp_kernel(
    const float* __restrict__ features,   // [BATCH][NPTS][FDIM]
    const float* __restrict__ W1,         // [FDIM][QDIM]
    const float* __restrict__ b1,         // [QDIM]
    const float* __restrict__ W2,         // [QDIM][QDIM]
    const float* __restrict__ b2,         // [QDIM]
    const unsigned long long* __restrict__ fparts,  // [BATCH][KSEL][G]
    float* __restrict__ out_q)            // [BATCH][KSEL][QDIM]
{
    const int bk = blockIdx.x;            // b*KSEL + k
    const int b  = bk / KSEL;
    const int q  = threadIdx.x;
    const int lane = q & 63;

    __shared__ float fr[FDIM];
    __shared__ float h[QDIM];
    __shared__ int s_idx;

    if (q < 64) {
        unsigned long long k = 0;
        if (lane < G) k = fparts[(size_t)bk * G + lane];
        #pragma unroll
        for (int off = 32; off > 0; off >>= 1) {
            unsigned long long o = __shfl_xor(k, off, 64);
            if (o > k) k = o;
        }
        if (lane == 0) s_idx = (int)(~(unsigned)(k & 0xFFFFFFFFull));
    }
    __syncthreads();

    const float* frow = features + ((size_t)b * NPTS + s_idx) * FDIM;
    if (q < FDIM) fr[q] = frow[q];
    __syncthreads();

    float acc = b1[q];
    #pragma unroll 8
    for (int f = 0; f < FDIM; ++f) acc += fr[f] * W1[f * QDIM + q];
    h[q] = fmaxf(acc, 0.0f);
    __syncthreads();

    float acc2 = b2[q];
    #pragma unroll 8
    for (int j = 0; j < QDIM; ++j) acc2 += h[j] * W2[j * QDIM + q];
    out_q[(size_t)bk * QDIM + q] = acc2;
}

extern "C" void kernel_launch(void* const* d_in, const int* in_sizes, int n_in,
                              void* d_out, int out_size, void* d_ws, size_t ws_size,
                              hipStream_t stream) {
    (void)in_sizes; (void)n_in; (void)out_size; (void)ws_size;
    const float* coords   = (const float*)d_in[0];
    const float* features = (const float*)d_in[1];
    const float* W1       = (const float*)d_in[2];
    const float* b1       = (const float*)d_in[3];
    const float* W2       = (const float*)d_in[4];
    const float* b2       = (const float*)d_in[5];

    float* out_q  = (float*)d_out;
    float* out_sc = out_q + (size_t)BATCH * KSEL * QDIM;

    char* ws = (char*)d_ws;
    unsigned long long* slots  = (unsigned long long*)ws;
    unsigned long long* fparts = (unsigned long long*)(ws + FPART_OFF);

    hipMemsetAsync(d_ws, 0, WS_TOTAL, stream);
    fps_kernel<<<BATCH * G, T, 0, stream>>>(coords, slots, fparts, out_sc);
    mlp_kernel<<<BATCH * KSEL, QDIM, 0, stream>>>(features, W1, b1, W2, b2,
                                                  fparts, out_q);
}

// Round 13
// 332.874 us; speedup vs baseline: 1.9599x; 1.2935x over previous
//
#include <hip/hip_runtime.h>

#define BATCH 4
#define NPTS  131072
#define KSEL  128
#define FDIM  96
#define QDIM  128

#define G   32                   // workgroups per batch
#define T   512                  // threads per workgroup
#define P   (NPTS / (G * T))     // 8 points per thread (registers)
#define NW  (T / 64)             // 8 waves per WG

#define AG __HIP_MEMORY_SCOPE_AGENT

// ---- workspace (exactly 256 KiB == proven budget) ----
// slots: per (batch, wg) one 1KiB-strided LINE (channel spreading); within the
//   line, TWO u64 words indexed by step parity (R11-proven race-free scheme):
//   a writer is at most 1 step ahead of any poller, and 1-step-ahead writes go
//   to the other parity word; stale same-parity values differ in tag.
//   word = (d2_bits<<32) | (m<<8) | s,  m = NPTS-1-n (17 bits, bits 8..24)
//   -> u64 max == (max d2, then min index); tag (low byte) never matches a
//   different step; memset(0) each launch prevents cross-replay aliasing.
// fparts[BATCH][KSEL][G] u64 : per-WG feat argmax partials (d2<<32 | ~n)
#define SLOT_STRIDE_U64 128                      // 1 KiB line stride
#define SLOTS_SZ  (BATCH * G * 1024)             // 131072
#define FPART_SZ  (BATCH * KSEL * G * 8)         // 131072
#define FPART_OFF (SLOTS_SZ)
#define WS_TOTAL  (SLOTS_SZ + FPART_SZ)          // 262144

// d2 exactly as numpy: (dx*dx + dy*dy) + dz*dz, no FMA contraction
__device__ __forceinline__ float d2_np(float ax, float ay, float az,
                                       float bx, float by, float bz) {
    float dx = __fsub_rn(ax, bx);
    float dy = __fsub_rn(ay, by);
    float dz = __fsub_rn(az, bz);
    return __fadd_rn(__fadd_rn(__fmul_rn(dx, dx), __fmul_rn(dy, dy)),
                     __fmul_rn(dz, dz));
}

__global__ __launch_bounds__(T) void fps_kernel(
    const float* __restrict__ coords,          // [BATCH][NPTS][3]
    unsigned long long* __restrict__ slots,    // strided lines, 2 parity words
    unsigned long long* __restrict__ fparts,   // [BATCH][KSEL][G]
    float* __restrict__ out_sc)                // [BATCH][KSEL][3]
{
    const int b    = blockIdx.x / G;
    const int wgb  = blockIdx.x % G;
    const int tid  = threadIdx.x;
    const int wid  = tid >> 6;
    const int lane = tid & 63;
    const float* cb = coords + (size_t)b * NPTS * 3;
    const int base = wgb * T + tid;            // stride G*T between my points

    __shared__ unsigned long long s_md[NW];
    __shared__ unsigned long long s_ft[NW];
    __shared__ float s_samp[KSEL][3];
    __shared__ float s_cur[3];

    float px[P], py[P], pz[P], md[P];
    #pragma unroll
    for (int j = 0; j < P; ++j) {
        int n = base + j * (G * T);
        px[j] = cb[n * 3 + 0];
        py[j] = cb[n * 3 + 1];
        pz[j] = cb[n * 3 + 2];
        md[j] = 1e10f;
    }

    float cx = cb[0], cy = cb[1], cz = cb[2];  // sample 0 = index 0
    if (tid == 0) {
        s_samp[0][0] = cx; s_samp[0][1] = cy; s_samp[0][2] = cz;
    }
    __syncthreads();

    for (int s = 1; s < KSEL; ++s) {
        const int pb = s & 1;                  // parity word within the line
        // update md; per-lane argmax of md (FPS) and of raw d2 (feat for s-1)
        float bm = -1.0f; unsigned bn = 0;
        float bd = -1.0f; unsigned fn = 0;
        #pragma unroll
        for (int j = 0; j < P; ++j) {
            float d2 = d2_np(px[j], py[j], pz[j], cx, cy, cz);
            unsigned n = (unsigned)(base + j * (G * T));
            if (d2 > bd) { bd = d2; fn = n; }
            float m = fminf(md[j], d2);
            md[j] = m;
            if (m > bm) { bm = m; bn = n; }
        }
        // pack: d2<<32 | (NPTS-1-n)<<8 | s  (max == max d2, then min n)
        unsigned long long kmd =
            ((unsigned long long)__float_as_uint(bm) << 32) |
            ((unsigned long long)(NPTS - 1 - bn) << 8) |
            (unsigned long long)(unsigned)s;
        unsigned long long kft =
            ((unsigned long long)__float_as_uint(bd) << 32) | (unsigned)(~fn);
        #pragma unroll
        for (int off = 32; off > 0; off >>= 1) {
            unsigned long long o1 = __shfl_xor(kmd, off, 64);
            unsigned long long o2 = __shfl_xor(kft, off, 64);
            if (o1 > kmd) kmd = o1;
            if (o2 > kft) kft = o2;
        }
        if (lane == 0) { s_md[wid] = kmd; s_ft[wid] = kft; }
        __syncthreads();                       // barrier 1: partials ready

        if (wid == 0) {
            // ---- critical path: merge 8 wave partials, publish, poll ----
            unsigned long long k1 = (lane < NW) ? s_md[lane] : 0;
            #pragma unroll
            for (int off = 4; off > 0; off >>= 1) {
                unsigned long long o = __shfl_xor(k1, off, 64);
                if (o > k1) k1 = o;
            }
            if (lane == 0)
                __hip_atomic_store(
                    &slots[(size_t)(b * G + wgb) * SLOT_STRIDE_U64 + pb],
                    k1, __ATOMIC_RELAXED, AG);
            // poll: 32 lanes, each its own 1KiB-strided line's parity word
            unsigned long long k = 0;
            if (lane < G) {
                const unsigned long long* p =
                    &slots[(size_t)(b * G + lane) * SLOT_STRIDE_U64 + pb];
                do {
                    k = __hip_atomic_load(p, __ATOMIC_RELAXED, AG);
                } while (((unsigned)k & 0xFFu) != (unsigned)s);
            }
            #pragma unroll
            for (int off = 32; off > 0; off >>= 1) {
                unsigned long long o = __shfl_xor(k, off, 64);
                if (o > k) k = o;
            }
            if (lane == 0) {
                unsigned m = ((unsigned)(k & 0xFFFFFFFFull)) >> 8;  // bits 8..24
                int idx = (int)(NPTS - 1u - m);
                float wx = cb[idx * 3 + 0];    // read-only, cacheable
                float wy = cb[idx * 3 + 1];
                float wz = cb[idx * 3 + 2];
                s_cur[0] = wx; s_cur[1] = wy; s_cur[2] = wz;
                s_samp[s][0] = wx; s_samp[s][1] = wy; s_samp[s][2] = wz;
            }
        } else if (wid == 1) {
            // feat merge/store for sample s-1: off the critical path
            unsigned long long k2 = (lane < NW) ? s_ft[lane] : 0;
            #pragma unroll
            for (int off = 4; off > 0; off >>= 1) {
                unsigned long long o = __shfl_xor(k2, off, 64);
                if (o > k2) k2 = o;
            }
            if (lane == 0)
                fparts[((size_t)b * KSEL + (s - 1)) * G + wgb] = k2;
        }
        __syncthreads();                       // barrier 2: winner broadcast
        cx = s_cur[0]; cy = s_cur[1]; cz = s_cur[2];
    }

    // feat partial for sample 127 (cx.. = sample 127 now)
    {
        float bd = -1.0f; unsigned fn = 0;
        #pragma unroll
        for (int j = 0; j < P; ++j) {
            float d2 = d2_np(px[j], py[j], pz[j], cx, cy, cz);
            unsigned n = (unsigned)(base + j * (G * T));
            if (d2 > bd) { bd = d2; fn = n; }
        }
        unsigned long long kft =
            ((unsigned long long)__float_as_uint(bd) << 32) | (unsigned)(~fn);
        #pragma unroll
        for (int off = 32; off > 0; off >>= 1) {
            unsigned long long o = __shfl_xor(kft, off, 64);
            if (o > kft) kft = o;
        }
        if (lane == 0) s_ft[wid] = kft;
        __syncthreads();
        if (tid == 0) {
            unsigned long long k = s_ft[0];
            #pragma unroll
            for (int w = 1; w < NW; ++w)
                if (s_ft[w] > k) k = s_ft[w];
            fparts[((size_t)b * KSEL + (KSEL - 1)) * G + wgb] = k;
        }
    }

    // wgb 0 dumps all sampled coords once (off critical path)
    if (wgb == 0 && tid < KSEL * 3) {
        const float* sf = &s_samp[0][0];
        out_sc[(size_t)b * KSEL * 3 + tid] = sf[tid];
    }
}

__global__ __launch_bounds__(QDIM) void mlp_kernel(
    const float* __restrict__ features,   // [BATCH][NPTS][FDIM]
    const float* __restrict__ W1,         // [FDIM][QDIM]
    const float* __restrict__ b1,         // [QDIM]
    const float* __restrict__ W2,         // [QDIM][QDIM]
    const float* __restrict__ b2,         // [QDIM]
    const unsigned long long* __restrict__ fparts,  // [BATCH][KSEL][G]
    float* __restrict__ out_q)            // [BATCH][KSEL][QDIM]
{
    const int bk = blockIdx.x;            // b*KSEL + k
    const int b  = bk / KSEL;
    const int q  = threadIdx.x;
    const int lane = q & 63;

    __shared__ float fr[FDIM];
    __shared__ float h[QDIM];
    __shared__ int s_idx;

    if (q < 64) {
        unsigned long long k = 0;
        if (lane < G) k = fparts[(size_t)bk * G + lane];
        #pragma unroll
        for (int off = 32; off > 0; off >>= 1) {
            unsigned long long o = __shfl_xor(k, off, 64);
            if (o > k) k = o;
        }
        if (lane == 0) s_idx = (int)(~(unsigned)(k & 0xFFFFFFFFull));
    }
    __syncthreads();

    const float* frow = features + ((size_t)b * NPTS + s_idx) * FDIM;
    if (q < FDIM) fr[q] = frow[q];
    __syncthreads();

    float acc = b1[q];
    #pragma unroll 8
    for (int f = 0; f < FDIM; ++f) acc += fr[f] * W1[f * QDIM + q];
    h[q] = fmaxf(acc, 0.0f);
    __syncthreads();

    float acc2 = b2[q];
    #pragma unroll 8
    for (int j = 0; j < QDIM; ++j) acc2 += h[j] * W2[j * QDIM + q];
    out_q[(size_t)bk * QDIM + q] = acc2;
}

extern "C" void kernel_launch(void* const* d_in, const int* in_sizes, int n_in,
                              void* d_out, int out_size, void* d_ws, size_t ws_size,
                              hipStream_t stream) {
    (void)in_sizes; (void)n_in; (void)out_size; (void)ws_size;
    const float* coords   = (const float*)d_in[0];
    const float* features = (const float*)d_in[1];
    const float* W1       = (const float*)d_in[2];
    const float* b1       = (const float*)d_in[3];
    const float* W2       = (const float*)d_in[4];
    const float* b2       = (const float*)d_in[5];

    float* out_q  = (float*)d_out;
    float* out_sc = out_q + (size_t)BATCH * KSEL * QDIM;

    char* ws = (char*)d_ws;
    unsigned long long* slots  = (unsigned long long*)ws;
    unsigned long long* fparts = (unsigned long long*)(ws + FPART_OFF);

    hipMemsetAsync(d_ws, 0, WS_TOTAL, stream);
    fps_kernel<<<BATCH * G, T, 0, stream>>>(coords, slots, fparts, out_sc);
    mlp_kernel<<<BATCH * KSEL, QDIM, 0, stream>>>(features, W1, b1, W2, b2,
                                                  fparts, out_q);
}